// Round 2
// baseline (114.218 us; speedup 1.0000x reference)
//
#include <hip/hip_runtime.h>
#include <hip/hip_bf16.h>
#include <stdint.h>

// ContrastiveLoss: N=8192, D=512 fp32 features, int labels {0,1}.
// out = mean_i [ (np_i * log(sum_exp_i) - sum_pos_i) / (np_i + 1e-8) ]
// R1: global_load_lds(16B) + XOR-swizzled LDS (bank-floor b128 reads).
// R2: upper-triangle tiles (2080). R5: fp8-e4m3 (x16 pre-scale; k
//     pre-permuted identically for A/B -> dot-invariant).
// R7: XCD swizzle. R9..R16: pipelined dbuf, [slot][row] PEP, coalesced
//     final. 112.5 us champion, sim 49.8 us (28% of fp8 MFMA peak).
// R17: kill the 2-phase drain stall (T3/T4-lite): 3 LDS buffers, depth-2
//     prefetch, raw s_barrier + counted s_waitcnt vmcnt(4) (never 0 in
//     steady state) instead of __syncthreads' implicit vmcnt(0) drain.
//     + T5 setprio around MFMA cluster. Epilogue: raw-acc sp with deferred
//     SIM_SCALE, int4 label loads.
// R18: resubmit of R17 (infra failure, theory untested); __expf only
//     (champion-proven), no exp2 builtin.

#define N_ROWS 8192
#define DIMF 512
#define DIMB 512
#define NB 64
#define NSLOT 128
#define SIM_SCALE 0.0390625f   // 10 / 256  (features pre-scaled by 16)

typedef float f32x4 __attribute__((ext_vector_type(4)));
typedef int64_t i64x2 __attribute__((ext_vector_type(2)));

__device__ static inline void gload_lds16(const uint8_t* g, uint8_t* l) {
    __builtin_amdgcn_global_load_lds(
        (const __attribute__((address_space(1))) unsigned int*)g,
        (__attribute__((address_space(3))) unsigned int*)l, 16, 0, 0);
}

// 4 waves/block, one row per wave: fp32 sumsq -> scale by 16/norm -> fp8,
// k-permuted per 64B tile: orig (c,q) byte-group -> q*16 + c*8 (dot-invariant
// since A and B sides use the same permutation). Block 0 zeroes out[0].
__global__ __launch_bounds__(256) void norm_kernel(const float* __restrict__ x,
                                                   uint8_t* __restrict__ f8,
                                                   float* __restrict__ out) {
    const int wave = threadIdx.x >> 6, t = threadIdx.x & 63;
    const int row = blockIdx.x * 4 + wave;
    const float4* xr = (const float4*)(x + (size_t)row * DIMF);
    float4 v0 = xr[2 * t];
    float4 v1 = xr[2 * t + 1];
    float ss = v0.x * v0.x + v0.y * v0.y + v0.z * v0.z + v0.w * v0.w +
               v1.x * v1.x + v1.y * v1.y + v1.z * v1.z + v1.w * v1.w;
#pragma unroll
    for (int off = 32; off >= 1; off >>= 1) ss += __shfl_xor(ss, off, 64);
    float s = 16.0f / fmaxf(sqrtf(ss), 1e-12f);
    int lo = 0, hi = 0;
    lo = __builtin_amdgcn_cvt_pk_fp8_f32(v0.x * s, v0.y * s, lo, false);
    lo = __builtin_amdgcn_cvt_pk_fp8_f32(v0.z * s, v0.w * s, lo, true);
    hi = __builtin_amdgcn_cvt_pk_fp8_f32(v1.x * s, v1.y * s, hi, false);
    hi = __builtin_amdgcn_cvt_pk_fp8_f32(v1.z * s, v1.w * s, hi, true);
    int2 pk;
    pk.x = lo;
    pk.y = hi;
    const int pos = (t >> 3) * 64 + (t & 3) * 16 + ((t >> 2) & 1) * 8;
    *(int2*)(f8 + (size_t)row * DIMB + pos) = pk;
    if (blockIdx.x == 0 && threadIdx.x == 0) out[0] = 0.0f;
}

// 128x128 tile/block (4 waves 2x2, each 64x64 via 4x4x2 MFMA 16x16x32 fp8).
// BK=64B, TRIPLE-buffered, depth-2 prefetch: at step kk the in-flight
// batches are {kk, kk+1}; wait vmcnt(4) retires batch kk (oldest 4 loads,
// in-order retirement), leaving kk+1 in flight across the raw s_barrier.
// Issue batch kk+2 into buf[(kk+2)%3] right after the barrier: that buffer
// was last read at kk-1, and every wave passed this barrier => safe.
// Latency budget per batch = 2 full compute phases (vs 1 before).
__global__ __launch_bounds__(256, 3) void sim_kernel(const uint8_t* __restrict__ f8,
                                                     const int* __restrict__ lab,
                                                     float2* __restrict__ PEP) {
    __shared__ __align__(16) uint8_t sA[3][128 * 64];
    __shared__ __align__(16) uint8_t sB[3][128 * 64];

    // XCD-locality swizzle (2080 = 8 * 260); decode upper-triangle index.
    const int tblk = (blockIdx.x & 7) * 260 + (blockIdx.x >> 3);
    int bi = (int)(64.5f - sqrtf(64.5f * 64.5f - 2.0f * (float)tblk));
    while (bi * (129 - bi) / 2 > tblk) --bi;
    while ((bi + 1) * (128 - bi) / 2 <= tblk) ++bi;
    const int bj = bi + (tblk - bi * (129 - bi) / 2);
    const bool diag = (bi == bj);

    const int t = threadIdx.x;
    const int iBase = bi * 128, jBase = bj * 128;
    const int lane = t & 63, wave = t >> 6;
    const int wm = wave >> 1, wn = wave & 1;
    const int lrow = lane & 15, quad = lane >> 4;

    const int sub = lane >> 2;
    const int lu = (lane & 3) ^ ((sub >> 1) & 3);
    const size_t gA0 = (size_t)(iBase + wave * 32 + sub) * DIMB + lu * 16;
    const size_t gB0 = (size_t)(jBase + wave * 32 + sub) * DIMB + lu * 16;

    f32x4 acc[4][4] = {};

    // Prologue: batches 0 and 1 into buffers 0 and 1.
#pragma unroll
    for (int b = 0; b < 2; ++b)
#pragma unroll
        for (int c = 0; c < 2; ++c) {
            gload_lds16(f8 + gA0 + (size_t)(c * 16) * DIMB + b * 64,
                        sA[b] + (wave * 32 + c * 16) * 64);
            gload_lds16(f8 + gB0 + (size_t)(c * 16) * DIMB + b * 64,
                        sB[b] + (wave * 32 + c * 16) * 64);
        }

#pragma unroll
    for (int kk = 0; kk < 8; ++kk) {
        const int cur = kk % 3;
        // Retire batch kk only (batch kk+1 stays in flight across the
        // barrier). Last step: nothing else in flight, drain fully.
        if (kk < 7)
            asm volatile("s_waitcnt vmcnt(4)" ::: "memory");
        else
            asm volatile("s_waitcnt vmcnt(0)" ::: "memory");
        __builtin_amdgcn_s_barrier();
        __builtin_amdgcn_sched_barrier(0);
        if (kk < 6) {
            const int nb = (kk + 2) % 3;
#pragma unroll
            for (int c = 0; c < 2; ++c) {
                gload_lds16(f8 + gA0 + (size_t)(c * 16) * DIMB + (kk + 2) * 64,
                            sA[nb] + (wave * 32 + c * 16) * 64);
                gload_lds16(f8 + gB0 + (size_t)(c * 16) * DIMB + (kk + 2) * 64,
                            sB[nb] + (wave * 32 + c * 16) * 64);
            }
        }
        const int pu = (quad ^ ((lrow >> 1) & 3)) * 16;
        i64x2 af[4], bfr[4];
#pragma unroll
        for (int m = 0; m < 4; ++m)
            af[m] = *(const i64x2*)(sA[cur] + (wm * 64 + m * 16 + lrow) * 64 + pu);
#pragma unroll
        for (int n = 0; n < 4; ++n)
            bfr[n] = *(const i64x2*)(sB[cur] + (wn * 64 + n * 16 + lrow) * 64 + pu);
        __builtin_amdgcn_s_setprio(1);
#pragma unroll
        for (int m = 0; m < 4; ++m)
#pragma unroll
            for (int n = 0; n < 4; ++n) {
                acc[m][n] = __builtin_amdgcn_mfma_f32_16x16x32_fp8_fp8(
                    af[m].x, bfr[n].x, acc[m][n], 0, 0, 0);
                acc[m][n] = __builtin_amdgcn_mfma_f32_16x16x32_fp8_fp8(
                    af[m].y, bfr[n].y, acc[m][n], 0, 0, 0);
            }
        __builtin_amdgcn_s_setprio(0);
    }

    // Register-only epilogue. C/D layout: col=lane&15, row=quad*4+reg.
    // sp/spc accumulate RAW acc; SIM_SCALE applied once after reductions.
    int labj[4];
#pragma unroll
    for (int n = 0; n < 4; ++n) labj[n] = lab[jBase + wn * 64 + n * 16 + lrow];

    const int slotR = 2 * bj + wn;  // rows of iBase
    const int slotC = 2 * bi + wm;  // cols of jBase
    float sec[4] = {0, 0, 0, 0}, spc[4] = {0, 0, 0, 0};

#pragma unroll
    for (int m = 0; m < 4; ++m) {
        const int rbase = wm * 64 + m * 16 + quad * 4;
        const int4 li4 = *(const int4*)(lab + iBase + rbase);
        float rE[4], rP[4];
#pragma unroll
        for (int e = 0; e < 4; ++e) {
            const int labi = ((const int*)&li4)[e];
            float se = 0.0f, sp = 0.0f;
            if (diag) {
                const int i = iBase + rbase + e;
#pragma unroll
                for (int n = 0; n < 4; ++n) {
                    const int j = jBase + wn * 64 + n * 16 + lrow;
                    const float tv = acc[m][n][e];
                    if (j != i) {
                        se += __expf(tv * SIM_SCALE);
                        if (labj[n] == labi) sp += tv;
                    }
                }
            } else {
#pragma unroll
                for (int n = 0; n < 4; ++n) {
                    const float tv = acc[m][n][e];
                    const float ex = __expf(tv * SIM_SCALE);
                    se += ex;
                    sec[n] += ex;
                    if (labj[n] == labi) {
                        sp += tv;
                        spc[n] += tv;
                    }
                }
            }
#pragma unroll
            for (int off = 8; off >= 1; off >>= 1) {
                se += __shfl_xor(se, off, 16);
                sp += __shfl_xor(sp, off, 16);
            }
            rE[e] = se;
            rP[e] = sp * SIM_SCALE;
        }
        if (lrow == 0) {
            // 4 consecutive rows -> 32B contiguous (two float4 stores)
            float2* dst = &PEP[(size_t)slotR * N_ROWS + iBase + rbase];
            float4 v0 = {rE[0], rP[0], rE[1], rP[1]};
            float4 v1 = {rE[2], rP[2], rE[3], rP[3]};
            *(float4*)dst = v0;
            *(float4*)(dst + 2) = v1;
        }
    }

    if (!diag) {
#pragma unroll
        for (int n = 0; n < 4; ++n) {
            sec[n] += __shfl_xor(sec[n], 16, 64);
            sec[n] += __shfl_xor(sec[n], 32, 64);
            spc[n] += __shfl_xor(spc[n], 16, 64);
            spc[n] += __shfl_xor(spc[n], 32, 64);
        }
        if (quad == 0) {
            // 16 lanes x consecutive j -> 128B contiguous per n
#pragma unroll
            for (int n = 0; n < 4; ++n) {
                const int j = jBase + wn * 64 + n * 16 + lrow;
                float2 v;
                v.x = sec[n];
                v.y = spc[n] * SIM_SCALE;
                PEP[(size_t)slotC * N_ROWS + j] = v;
            }
        }
    }
}

// 128 blocks x 64 rows, [slot][row] layout. Thread (rr = t&63, q = t>>6):
// sums slots 32q..32q+32 for row r0+rr -- each wave instr reads 64
// consecutive rows of one slot = 512B contiguous. Quarter-fold via LDS,
// wave 0 computes per-row loss, reduces, atomicAdds the mean.
__global__ __launch_bounds__(256) void final_kernel(const float2* __restrict__ PEP,
                                                    const int* __restrict__ lab,
                                                    float* __restrict__ out) {
    __shared__ float sE[256], sP[256], sh[4];
    __shared__ float shc;
    const int t = threadIdx.x;
    const int rr = t & 63, q = t >> 6;

    int cl = 0;
#pragma unroll 8
    for (int s = t; s < N_ROWS; s += 256) cl += lab[s];
#pragma unroll
    for (int off = 32; off >= 1; off >>= 1) cl += __shfl_xor(cl, off, 64);
    if (rr == 0) sh[q] = (float)cl;
    __syncthreads();
    if (t == 0) shc = sh[0] + sh[1] + sh[2] + sh[3];

    const int r0 = blockIdx.x * 64;
    float se = 0.0f, sp = 0.0f;
#pragma unroll 8
    for (int v = 0; v < 32; ++v) {
        const float2 x = PEP[(size_t)(q * 32 + v) * N_ROWS + r0 + rr];
        se += x.x;
        sp += x.y;
    }
    sE[t] = se;
    sP[t] = sp;
    __syncthreads();

    float local = 0.0f;
    if (q == 0) {
        se = sE[rr] + sE[64 + rr] + sE[128 + rr] + sE[192 + rr];
        sp = sP[rr] + sP[64 + rr] + sP[128 + rr] + sP[192 + rr];
        const float c1 = shc;
        const int li = lab[r0 + rr];
        const float np = (li ? c1 : (float)N_ROWS - c1) - 1.0f;
        local = (np * __logf(se) - sp) / (np + 1e-8f);
#pragma unroll
        for (int off = 32; off >= 1; off >>= 1) local += __shfl_xor(local, off, 64);
    }
    if (t == 0) atomicAdd(out, local * (1.0f / (float)N_ROWS));
}

extern "C" void kernel_launch(void* const* d_in, const int* in_sizes, int n_in,
                              void* d_out, int out_size, void* d_ws, size_t ws_size,
                              hipStream_t stream) {
    const float* features = (const float*)d_in[0];
    const int* labels = (const int*)d_in[1];
    float* out = (float*)d_out;

    char* ws = (char*)d_ws;
    uint8_t* f8 = (uint8_t*)ws;                              // 4 MiB
    float2* PEP = (float2*)(ws + (size_t)N_ROWS * DIMB);     // 8 MiB [slot][row]

    norm_kernel<<<N_ROWS / 4, 256, 0, stream>>>(features, f8, out);
    sim_kernel<<<NB * (NB + 1) / 2, 256, 0, stream>>>(f8, labels, PEP);
    final_kernel<<<128, 256, 0, stream>>>(PEP, labels, out);
}

// Round 3
// 109.479 us; speedup vs baseline: 1.0433x; 1.0433x over previous
//
#include <hip/hip_runtime.h>
#include <hip/hip_bf16.h>
#include <stdint.h>

// ContrastiveLoss: N=8192, D=512 fp32 features, int labels {0,1}.
// out = mean_i [ (np_i * log(sum_exp_i) - sum_pos_i) / (np_i + 1e-8) ]
// R1: global_load_lds(16B) + XOR-swizzled LDS (bank-floor b128 reads).
// R2: upper-triangle tiles (2080). R5: fp8-e4m3 (x16 pre-scale; k
//     pre-permuted identically for A/B -> dot-invariant).
// R7: XCD swizzle. R9..R16: pipelined dbuf, [slot][row] PEP, coalesced
//     final. 112.5 us champion, sim 49.8 us (28% of fp8 MFMA peak).
// R17/R18: counted-vmcnt 3-buf pipeline -> sim 48.2 (FLAT; drain-stall
//     theory falsified; occupancy 24% with no slowdown -> not latency-bound).
// R19: LDS-pipe theory: 144 ds_bpermute shfls/thread in epilogue saturate
//     the LDS pipe (~3.7k cyc/block + lgkm chains). Move the width-16
//     butterflies (128 of them) to DPP row_ror VALU adds (zero LDS traffic,
//     2-cyc issue). Cross-quad col-side (16 shfls) stays.

#define N_ROWS 8192
#define DIMF 512
#define DIMB 512
#define NB 64
#define NSLOT 128
#define SIM_SCALE 0.0390625f   // 10 / 256  (features pre-scaled by 16)

typedef float f32x4 __attribute__((ext_vector_type(4)));
typedef int64_t i64x2 __attribute__((ext_vector_type(2)));

__device__ static inline void gload_lds16(const uint8_t* g, uint8_t* l) {
    __builtin_amdgcn_global_load_lds(
        (const __attribute__((address_space(1))) unsigned int*)g,
        (__attribute__((address_space(3))) unsigned int*)l, 16, 0, 0);
}

// Full 16-lane-row sum via DPP rotate-reduce (VALU only, no LDS pipe).
// row_ror:N dpp_ctrl = 0x120|N. Offsets 8,4,2,1 span the row; every lane
// ends with the row total (same as 4-level xor butterfly over width 16).
__device__ static inline float rowsum16(float s) {
    s += __int_as_float(__builtin_amdgcn_update_dpp(
        0, __float_as_int(s), 0x128, 0xf, 0xf, false));
    s += __int_as_float(__builtin_amdgcn_update_dpp(
        0, __float_as_int(s), 0x124, 0xf, 0xf, false));
    s += __int_as_float(__builtin_amdgcn_update_dpp(
        0, __float_as_int(s), 0x122, 0xf, 0xf, false));
    s += __int_as_float(__builtin_amdgcn_update_dpp(
        0, __float_as_int(s), 0x121, 0xf, 0xf, false));
    return s;
}

// 4 waves/block, one row per wave: fp32 sumsq -> scale by 16/norm -> fp8,
// k-permuted per 64B tile: orig (c,q) byte-group -> q*16 + c*8 (dot-invariant
// since A and B sides use the same permutation). Block 0 zeroes out[0].
__global__ __launch_bounds__(256) void norm_kernel(const float* __restrict__ x,
                                                   uint8_t* __restrict__ f8,
                                                   float* __restrict__ out) {
    const int wave = threadIdx.x >> 6, t = threadIdx.x & 63;
    const int row = blockIdx.x * 4 + wave;
    const float4* xr = (const float4*)(x + (size_t)row * DIMF);
    float4 v0 = xr[2 * t];
    float4 v1 = xr[2 * t + 1];
    float ss = v0.x * v0.x + v0.y * v0.y + v0.z * v0.z + v0.w * v0.w +
               v1.x * v1.x + v1.y * v1.y + v1.z * v1.z + v1.w * v1.w;
#pragma unroll
    for (int off = 32; off >= 1; off >>= 1) ss += __shfl_xor(ss, off, 64);
    float s = 16.0f / fmaxf(sqrtf(ss), 1e-12f);
    int lo = 0, hi = 0;
    lo = __builtin_amdgcn_cvt_pk_fp8_f32(v0.x * s, v0.y * s, lo, false);
    lo = __builtin_amdgcn_cvt_pk_fp8_f32(v0.z * s, v0.w * s, lo, true);
    hi = __builtin_amdgcn_cvt_pk_fp8_f32(v1.x * s, v1.y * s, hi, false);
    hi = __builtin_amdgcn_cvt_pk_fp8_f32(v1.z * s, v1.w * s, hi, true);
    int2 pk;
    pk.x = lo;
    pk.y = hi;
    const int pos = (t >> 3) * 64 + (t & 3) * 16 + ((t >> 2) & 1) * 8;
    *(int2*)(f8 + (size_t)row * DIMB + pos) = pk;
    if (blockIdx.x == 0 && threadIdx.x == 0) out[0] = 0.0f;
}

// 128x128 tile/block (4 waves 2x2, each 64x64 via 4x4x2 MFMA 16x16x32 fp8).
// BK=64B, TRIPLE-buffered, depth-2 prefetch, counted vmcnt (R18 structure).
__global__ __launch_bounds__(256, 3) void sim_kernel(const uint8_t* __restrict__ f8,
                                                     const int* __restrict__ lab,
                                                     float2* __restrict__ PEP) {
    __shared__ __align__(16) uint8_t sA[3][128 * 64];
    __shared__ __align__(16) uint8_t sB[3][128 * 64];

    // XCD-locality swizzle (2080 = 8 * 260); decode upper-triangle index.
    const int tblk = (blockIdx.x & 7) * 260 + (blockIdx.x >> 3);
    int bi = (int)(64.5f - sqrtf(64.5f * 64.5f - 2.0f * (float)tblk));
    while (bi * (129 - bi) / 2 > tblk) --bi;
    while ((bi + 1) * (128 - bi) / 2 <= tblk) ++bi;
    const int bj = bi + (tblk - bi * (129 - bi) / 2);
    const bool diag = (bi == bj);

    const int t = threadIdx.x;
    const int iBase = bi * 128, jBase = bj * 128;
    const int lane = t & 63, wave = t >> 6;
    const int wm = wave >> 1, wn = wave & 1;
    const int lrow = lane & 15, quad = lane >> 4;

    const int sub = lane >> 2;
    const int lu = (lane & 3) ^ ((sub >> 1) & 3);
    const size_t gA0 = (size_t)(iBase + wave * 32 + sub) * DIMB + lu * 16;
    const size_t gB0 = (size_t)(jBase + wave * 32 + sub) * DIMB + lu * 16;

    f32x4 acc[4][4] = {};

    // Prologue: batches 0 and 1 into buffers 0 and 1.
#pragma unroll
    for (int b = 0; b < 2; ++b)
#pragma unroll
        for (int c = 0; c < 2; ++c) {
            gload_lds16(f8 + gA0 + (size_t)(c * 16) * DIMB + b * 64,
                        sA[b] + (wave * 32 + c * 16) * 64);
            gload_lds16(f8 + gB0 + (size_t)(c * 16) * DIMB + b * 64,
                        sB[b] + (wave * 32 + c * 16) * 64);
        }

#pragma unroll
    for (int kk = 0; kk < 8; ++kk) {
        const int cur = kk % 3;
        // Retire batch kk only (batch kk+1 stays in flight across the
        // barrier). Last step: nothing else in flight, drain fully.
        if (kk < 7)
            asm volatile("s_waitcnt vmcnt(4)" ::: "memory");
        else
            asm volatile("s_waitcnt vmcnt(0)" ::: "memory");
        __builtin_amdgcn_s_barrier();
        __builtin_amdgcn_sched_barrier(0);
        if (kk < 6) {
            const int nb = (kk + 2) % 3;
#pragma unroll
            for (int c = 0; c < 2; ++c) {
                gload_lds16(f8 + gA0 + (size_t)(c * 16) * DIMB + (kk + 2) * 64,
                            sA[nb] + (wave * 32 + c * 16) * 64);
                gload_lds16(f8 + gB0 + (size_t)(c * 16) * DIMB + (kk + 2) * 64,
                            sB[nb] + (wave * 32 + c * 16) * 64);
            }
        }
        const int pu = (quad ^ ((lrow >> 1) & 3)) * 16;
        i64x2 af[4], bfr[4];
#pragma unroll
        for (int m = 0; m < 4; ++m)
            af[m] = *(const i64x2*)(sA[cur] + (wm * 64 + m * 16 + lrow) * 64 + pu);
#pragma unroll
        for (int n = 0; n < 4; ++n)
            bfr[n] = *(const i64x2*)(sB[cur] + (wn * 64 + n * 16 + lrow) * 64 + pu);
        __builtin_amdgcn_s_setprio(1);
#pragma unroll
        for (int m = 0; m < 4; ++m)
#pragma unroll
            for (int n = 0; n < 4; ++n) {
                acc[m][n] = __builtin_amdgcn_mfma_f32_16x16x32_fp8_fp8(
                    af[m].x, bfr[n].x, acc[m][n], 0, 0, 0);
                acc[m][n] = __builtin_amdgcn_mfma_f32_16x16x32_fp8_fp8(
                    af[m].y, bfr[n].y, acc[m][n], 0, 0, 0);
            }
        __builtin_amdgcn_s_setprio(0);
    }

    // Register-only epilogue. C/D layout: col=lane&15, row=quad*4+reg.
    // sp/spc accumulate RAW acc; SIM_SCALE applied once after reductions.
    // Row-side reductions are DPP row_ror (VALU); only the cheap cross-quad
    // col-side uses __shfl_xor (16 ops total).
    int labj[4];
#pragma unroll
    for (int n = 0; n < 4; ++n) labj[n] = lab[jBase + wn * 64 + n * 16 + lrow];

    const int slotR = 2 * bj + wn;  // rows of iBase
    const int slotC = 2 * bi + wm;  // cols of jBase
    float sec[4] = {0, 0, 0, 0}, spc[4] = {0, 0, 0, 0};

#pragma unroll
    for (int m = 0; m < 4; ++m) {
        const int rbase = wm * 64 + m * 16 + quad * 4;
        const int4 li4 = *(const int4*)(lab + iBase + rbase);
        float rE[4], rP[4];
#pragma unroll
        for (int e = 0; e < 4; ++e) {
            const int labi = ((const int*)&li4)[e];
            float se = 0.0f, sp = 0.0f;
            if (diag) {
                const int i = iBase + rbase + e;
#pragma unroll
                for (int n = 0; n < 4; ++n) {
                    const int j = jBase + wn * 64 + n * 16 + lrow;
                    const float tv = acc[m][n][e];
                    if (j != i) {
                        se += __expf(tv * SIM_SCALE);
                        if (labj[n] == labi) sp += tv;
                    }
                }
            } else {
#pragma unroll
                for (int n = 0; n < 4; ++n) {
                    const float tv = acc[m][n][e];
                    const float ex = __expf(tv * SIM_SCALE);
                    se += ex;
                    sec[n] += ex;
                    if (labj[n] == labi) {
                        sp += tv;
                        spc[n] += tv;
                    }
                }
            }
            rE[e] = rowsum16(se);
            rP[e] = rowsum16(sp) * SIM_SCALE;
        }
        if (lrow == 0) {
            // 4 consecutive rows -> 32B contiguous (two float4 stores)
            float2* dst = &PEP[(size_t)slotR * N_ROWS + iBase + rbase];
            float4 v0 = {rE[0], rP[0], rE[1], rP[1]};
            float4 v1 = {rE[2], rP[2], rE[3], rP[3]};
            *(float4*)dst = v0;
            *(float4*)(dst + 2) = v1;
        }
    }

    if (!diag) {
#pragma unroll
        for (int n = 0; n < 4; ++n) {
            sec[n] += __shfl_xor(sec[n], 16, 64);
            sec[n] += __shfl_xor(sec[n], 32, 64);
            spc[n] += __shfl_xor(spc[n], 16, 64);
            spc[n] += __shfl_xor(spc[n], 32, 64);
        }
        if (quad == 0) {
            // 16 lanes x consecutive j -> 128B contiguous per n
#pragma unroll
            for (int n = 0; n < 4; ++n) {
                const int j = jBase + wn * 64 + n * 16 + lrow;
                float2 v;
                v.x = sec[n];
                v.y = spc[n] * SIM_SCALE;
                PEP[(size_t)slotC * N_ROWS + j] = v;
            }
        }
    }
}

// 128 blocks x 64 rows, [slot][row] layout. Thread (rr = t&63, q = t>>6):
// sums slots 32q..32q+32 for row r0+rr -- each wave instr reads 64
// consecutive rows of one slot = 512B contiguous. Quarter-fold via LDS,
// wave 0 computes per-row loss, reduces, atomicAdds the mean.
__global__ __launch_bounds__(256) void final_kernel(const float2* __restrict__ PEP,
                                                    const int* __restrict__ lab,
                                                    float* __restrict__ out) {
    __shared__ float sE[256], sP[256], sh[4];
    __shared__ float shc;
    const int t = threadIdx.x;
    const int rr = t & 63, q = t >> 6;

    int cl = 0;
#pragma unroll 8
    for (int s = t; s < N_ROWS; s += 256) cl += lab[s];
#pragma unroll
    for (int off = 32; off >= 1; off >>= 1) cl += __shfl_xor(cl, off, 64);
    if (rr == 0) sh[q] = (float)cl;
    __syncthreads();
    if (t == 0) shc = sh[0] + sh[1] + sh[2] + sh[3];

    const int r0 = blockIdx.x * 64;
    float se = 0.0f, sp = 0.0f;
#pragma unroll 8
    for (int v = 0; v < 32; ++v) {
        const float2 x = PEP[(size_t)(q * 32 + v) * N_ROWS + r0 + rr];
        se += x.x;
        sp += x.y;
    }
    sE[t] = se;
    sP[t] = sp;
    __syncthreads();

    float local = 0.0f;
    if (q == 0) {
        se = sE[rr] + sE[64 + rr] + sE[128 + rr] + sE[192 + rr];
        sp = sP[rr] + sP[64 + rr] + sP[128 + rr] + sP[192 + rr];
        const float c1 = shc;
        const int li = lab[r0 + rr];
        const float np = (li ? c1 : (float)N_ROWS - c1) - 1.0f;
        local = (np * __logf(se) - sp) / (np + 1e-8f);
#pragma unroll
        for (int off = 32; off >= 1; off >>= 1) local += __shfl_xor(local, off, 64);
    }
    if (t == 0) atomicAdd(out, local * (1.0f / (float)N_ROWS));
}

extern "C" void kernel_launch(void* const* d_in, const int* in_sizes, int n_in,
                              void* d_out, int out_size, void* d_ws, size_t ws_size,
                              hipStream_t stream) {
    const float* features = (const float*)d_in[0];
    const int* labels = (const int*)d_in[1];
    float* out = (float*)d_out;

    char* ws = (char*)d_ws;
    uint8_t* f8 = (uint8_t*)ws;                              // 4 MiB
    float2* PEP = (float2*)(ws + (size_t)N_ROWS * DIMB);     // 8 MiB [slot][row]

    norm_kernel<<<N_ROWS / 4, 256, 0, stream>>>(features, f8, out);
    sim_kernel<<<NB * (NB + 1) / 2, 256, 0, stream>>>(f8, labels, PEP);
    final_kernel<<<128, 256, 0, stream>>>(PEP, labels, out);
}